// Round 1
// baseline (340.572 us; speedup 1.0000x reference)
//
#include <hip/hip_runtime.h>
#include <hip/hip_bf16.h>

typedef __attribute__((ext_vector_type(8))) short bf16x8;
typedef __attribute__((ext_vector_type(4))) float f32x4;
typedef unsigned short u16;

#define DEV static __device__ __forceinline__

DEV u16 f2bf(float f) {
  union { float f; unsigned u; } v; v.f = f;
  return (u16)((v.u + 0x7FFFu + ((v.u >> 16) & 1u)) >> 16);
}

// ---------------------------------------------------------------- convert
// x: 4*2048*512 f32 -> bf16 ; Wq/Wk/Wv -> Wb[1536][512] ; Wo -> Wob[512][512]
__global__ __launch_bounds__(256) void cvt_kernel(
    const float* __restrict__ x, const float* __restrict__ Wq,
    const float* __restrict__ Wk, const float* __restrict__ Wv,
    const float* __restrict__ Wo, u16* __restrict__ xb,
    u16* __restrict__ Wb, u16* __restrict__ Wob) {
  int g = blockIdx.x * 256 + threadIdx.x;
  if (g < 1048576) {  // x: 4194304 / 4
    float4 v = ((const float4*)x)[g];
    ushort4 o;
    o.x = f2bf(v.x); o.y = f2bf(v.y); o.z = f2bf(v.z); o.w = f2bf(v.w);
    ((ushort4*)xb)[g] = o;
  } else {
    int t = g - 1048576;           // 4 * 65536 weight groups
    int w = t >> 16;
    int off = t & 65535;
    const float* src = (w == 0) ? Wq : (w == 1) ? Wk : (w == 2) ? Wv : Wo;
    u16* dst = (w < 3) ? (Wb + (size_t)w * 262144) : Wob;
    float4 v = ((const float4*)src)[off];
    ushort4 o;
    o.x = f2bf(v.x); o.y = f2bf(v.y); o.z = f2bf(v.z); o.w = f2bf(v.w);
    ((ushort4*)dst)[off] = o;
  }
}

// ---------------------------------------------------------------- QKV GEMM
// C[8192][1536] = xb[8192][512] @ Wb[1536][512]^T + bias
// n<1024 -> QK[m][n] (Q cols 0-511, K cols 512-1023), n>=1024 -> Vt transposed
__global__ __launch_bounds__(256) void gemm_qkv(
    const u16* __restrict__ xb, const u16* __restrict__ Wb,
    const float* __restrict__ bq, const float* __restrict__ bk,
    const float* __restrict__ bv, u16* __restrict__ QK, u16* __restrict__ Vt) {
  __shared__ __align__(16) u16 As[128 * 32];
  __shared__ __align__(16) u16 Bs[128 * 32];
  const int tid = threadIdx.x, lane = tid & 63, wv = tid >> 6;
  const int fr = lane & 15, fg = lane >> 4;
  const int wr = wv >> 1, wc = wv & 1;
  const int m0 = blockIdx.x * 128, n0 = blockIdx.y * 128;
  f32x4 acc[4][4] = {};
  const int c0 = wv * 128;
  for (int kt = 0; kt < 512; kt += 32) {
#pragma unroll
    for (int i = 0; i < 2; ++i) {
      int c = c0 + i * 64 + lane;
      int row = c >> 2, cg = c & 3;
      const u16* ga = xb + (size_t)(m0 + row) * 512 + kt + cg * 8;
      const u16* gb = Wb + (size_t)(n0 + row) * 512 + kt + cg * 8;
      __builtin_amdgcn_global_load_lds(
          (const __attribute__((address_space(1))) void*)ga,
          (__attribute__((address_space(3))) void*)(As + (c0 + i * 64) * 8), 16, 0, 0);
      __builtin_amdgcn_global_load_lds(
          (const __attribute__((address_space(1))) void*)gb,
          (__attribute__((address_space(3))) void*)(Bs + (c0 + i * 64) * 8), 16, 0, 0);
    }
    __syncthreads();
    bf16x8 af[4], bf[4];
#pragma unroll
    for (int mi = 0; mi < 4; ++mi)
      af[mi] = *(const bf16x8*)(As + (wr * 64 + mi * 16 + fr) * 32 + fg * 8);
#pragma unroll
    for (int ni = 0; ni < 4; ++ni)
      bf[ni] = *(const bf16x8*)(Bs + (wc * 64 + ni * 16 + fr) * 32 + fg * 8);
#pragma unroll
    for (int mi = 0; mi < 4; ++mi)
#pragma unroll
      for (int ni = 0; ni < 4; ++ni)
        acc[mi][ni] = __builtin_amdgcn_mfma_f32_16x16x32_bf16(af[mi], bf[ni], acc[mi][ni], 0, 0, 0);
    __syncthreads();
  }
#pragma unroll
  for (int ni = 0; ni < 4; ++ni) {
    int n = n0 + wc * 64 + ni * 16 + fr;
    float bias = (n < 512) ? bq[n] : (n < 1024) ? bk[n - 512] : bv[n - 1024];
#pragma unroll
    for (int mi = 0; mi < 4; ++mi) {
#pragma unroll
      for (int r = 0; r < 4; ++r) {
        int m = m0 + wr * 64 + mi * 16 + fg * 4 + r;
        u16 val = f2bf(acc[mi][ni][r] + bias);
        if (n < 1024)
          QK[(size_t)m * 1024 + n] = val;
        else {
          int bb = m >> 11, t = m & 2047;
          Vt[((size_t)bb * 512 + (n - 1024)) * 2048 + t] = val;
        }
      }
    }
  }
}

// ---------------------------------------------------------------- attention
// block: (b, h, 128 q rows). 4 waves x 32 q rows, wave-private, no barriers.
__global__ __launch_bounds__(256) void attn_kernel(
    const u16* __restrict__ QK, const u16* __restrict__ Vt,
    const unsigned char* __restrict__ mask, float* __restrict__ attn,
    u16* __restrict__ ctx) {
  __shared__ __align__(16) u16 PL[4][2][16][32];
  const int tid = threadIdx.x, lane = tid & 63, wv = tid >> 6;
  const int fr = lane & 15, fg = lane >> 4;
  const int b = blockIdx.x >> 7, h = (blockIdx.x >> 4) & 7, qt = blockIdx.x & 15;
  const int q0 = qt * 128 + wv * 32;
  const size_t tok0 = (size_t)b * 2048;
  const u16* Qbase = QK + tok0 * 1024 + h * 64;
  const u16* Kbase = QK + tok0 * 1024 + 512 + h * 64;
  const u16* Vbase = Vt + ((size_t)b * 512 + h * 64) * 2048;

  bf16x8 aq[2][2];
#pragma unroll
  for (int q2 = 0; q2 < 2; ++q2)
#pragma unroll
    for (int c = 0; c < 2; ++c)
      aq[q2][c] = *(const bf16x8*)(Qbase + (size_t)(q0 + q2 * 16 + fr) * 1024 + c * 32 + fg * 8);

  float mrow[8], srow[8];
#pragma unroll
  for (int i = 0; i < 8; ++i) { mrow[i] = -1e30f; srow[i] = 0.f; }

  // ---- pass A: online row max / exp-sum
  for (int kt = 0; kt < 128; ++kt) {
    const int key = kt * 16 + fr;
    const u16* kp = Kbase + (size_t)key * 1024;
    bf16x8 kf0 = *(const bf16x8*)(kp + fg * 8);
    bf16x8 kf1 = *(const bf16x8*)(kp + 32 + fg * 8);
    float cutb = -0.5f * fabsf((float)key - 1024.0f);
    if (mask[tok0 + key]) cutb = -1e30f;
#pragma unroll
    for (int q2 = 0; q2 < 2; ++q2) {
      f32x4 a = {0.f, 0.f, 0.f, 0.f};
      a = __builtin_amdgcn_mfma_f32_16x16x32_bf16(aq[q2][0], kf0, a, 0, 0, 0);
      a = __builtin_amdgcn_mfma_f32_16x16x32_bf16(aq[q2][1], kf1, a, 0, 0, 0);
#pragma unroll
      for (int r = 0; r < 4; ++r) {
        const int idx = q2 * 4 + r;
        const int ii = q0 + q2 * 16 + fg * 4 + r;
        float S = a[r] * 0.125f - 0.02f * fabsf((float)(ii - key)) + cutb;
        float m = mrow[idx];
        float mn = fmaxf(m, S);
        float e = __expf(fminf(m, S) - mn);   // one exp per update
        srow[idx] = (S > m) ? (srow[idx] * e + 1.0f) : (srow[idx] + e);
        mrow[idx] = mn;
      }
    }
  }
  // reduce (m,s) across the 16 lanes of each group (cols)
#pragma unroll
  for (int d = 1; d < 16; d <<= 1) {
#pragma unroll
    for (int i = 0; i < 8; ++i) {
      float mo = __shfl_xor(mrow[i], d, 64);
      float so = __shfl_xor(srow[i], d, 64);
      float mn = fmaxf(mrow[i], mo);
      srow[i] = srow[i] * __expf(mrow[i] - mn) + so * __expf(mo - mn);
      mrow[i] = mn;
    }
  }
  float rinv[8];
#pragma unroll
  for (int i = 0; i < 8; ++i) rinv[i] = 1.0f / srow[i];

  f32x4 cacc[2][4] = {};
  float* attn_bh = attn + ((size_t)b * 8 + h) * 2048 * 2048;

  // ---- pass B: recompute S, write normalized P, accumulate PV
  for (int kc = 0; kc < 64; ++kc) {
    const int kk0 = kc * 32;
#pragma unroll
    for (int t = 0; t < 2; ++t) {
      const int key = kk0 + t * 16 + fr;
      const u16* kp = Kbase + (size_t)key * 1024;
      bf16x8 kf0 = *(const bf16x8*)(kp + fg * 8);
      bf16x8 kf1 = *(const bf16x8*)(kp + 32 + fg * 8);
      float cutb = -0.5f * fabsf((float)key - 1024.0f);
      if (mask[tok0 + key]) cutb = -1e30f;
#pragma unroll
      for (int q2 = 0; q2 < 2; ++q2) {
        f32x4 a = {0.f, 0.f, 0.f, 0.f};
        a = __builtin_amdgcn_mfma_f32_16x16x32_bf16(aq[q2][0], kf0, a, 0, 0, 0);
        a = __builtin_amdgcn_mfma_f32_16x16x32_bf16(aq[q2][1], kf1, a, 0, 0, 0);
#pragma unroll
        for (int r = 0; r < 4; ++r) {
          const int idx = q2 * 4 + r;
          const int ii = q0 + q2 * 16 + fg * 4 + r;
          float S = a[r] * 0.125f - 0.02f * fabsf((float)(ii - key)) + cutb;
          float P = __expf(S - mrow[idx]) * rinv[idx];
          attn_bh[(size_t)ii * 2048 + key] = P;          // coalesced 64B segs
          PL[wv][q2][fg * 4 + r][t * 16 + fr] = f2bf(P); // LDS round-trip
        }
      }
    }
    bf16x8 pa[2];
#pragma unroll
    for (int q2 = 0; q2 < 2; ++q2)
      pa[q2] = *(const bf16x8*)(&PL[wv][q2][fr][fg * 8]);
#pragma unroll
    for (int c4 = 0; c4 < 4; ++c4) {
      bf16x8 bvf = *(const bf16x8*)(Vbase + (size_t)(c4 * 16 + fr) * 2048 + kk0 + fg * 8);
#pragma unroll
      for (int q2 = 0; q2 < 2; ++q2)
        cacc[q2][c4] = __builtin_amdgcn_mfma_f32_16x16x32_bf16(pa[q2], bvf, cacc[q2][c4], 0, 0, 0);
    }
  }
  // ctx out (bf16, [8192][512])
#pragma unroll
  for (int q2 = 0; q2 < 2; ++q2)
#pragma unroll
    for (int c4 = 0; c4 < 4; ++c4)
#pragma unroll
      for (int r = 0; r < 4; ++r) {
        int q = q0 + q2 * 16 + fg * 4 + r;
        ctx[(tok0 + q) * 512 + h * 64 + c4 * 16 + fr] = f2bf(cacc[q2][c4][r]);
      }
}

// ---------------------------------------------------------------- out GEMM
// out[8192][512] = ctx[8192][512] @ Wob[512][512]^T + bo  (fp32 out)
__global__ __launch_bounds__(256) void gemm_out(
    const u16* __restrict__ ctx, const u16* __restrict__ Wob,
    const float* __restrict__ bo, float* __restrict__ out) {
  __shared__ __align__(16) u16 As[128 * 32];
  __shared__ __align__(16) u16 Bs[128 * 32];
  const int tid = threadIdx.x, lane = tid & 63, wv = tid >> 6;
  const int fr = lane & 15, fg = lane >> 4;
  const int wr = wv >> 1, wc = wv & 1;
  const int m0 = blockIdx.x * 128, n0 = blockIdx.y * 128;
  f32x4 acc[4][4] = {};
  const int c0 = wv * 128;
  for (int kt = 0; kt < 512; kt += 32) {
#pragma unroll
    for (int i = 0; i < 2; ++i) {
      int c = c0 + i * 64 + lane;
      int row = c >> 2, cg = c & 3;
      const u16* ga = ctx + (size_t)(m0 + row) * 512 + kt + cg * 8;
      const u16* gb = Wob + (size_t)(n0 + row) * 512 + kt + cg * 8;
      __builtin_amdgcn_global_load_lds(
          (const __attribute__((address_space(1))) void*)ga,
          (__attribute__((address_space(3))) void*)(As + (c0 + i * 64) * 8), 16, 0, 0);
      __builtin_amdgcn_global_load_lds(
          (const __attribute__((address_space(1))) void*)gb,
          (__attribute__((address_space(3))) void*)(Bs + (c0 + i * 64) * 8), 16, 0, 0);
    }
    __syncthreads();
    bf16x8 af[4], bf[4];
#pragma unroll
    for (int mi = 0; mi < 4; ++mi)
      af[mi] = *(const bf16x8*)(As + (wr * 64 + mi * 16 + fr) * 32 + fg * 8);
#pragma unroll
    for (int ni = 0; ni < 4; ++ni)
      bf[ni] = *(const bf16x8*)(Bs + (wc * 64 + ni * 16 + fr) * 32 + fg * 8);
#pragma unroll
    for (int mi = 0; mi < 4; ++mi)
#pragma unroll
      for (int ni = 0; ni < 4; ++ni)
        acc[mi][ni] = __builtin_amdgcn_mfma_f32_16x16x32_bf16(af[mi], bf[ni], acc[mi][ni], 0, 0, 0);
    __syncthreads();
  }
#pragma unroll
  for (int ni = 0; ni < 4; ++ni) {
    int n = n0 + wc * 64 + ni * 16 + fr;
    float bias = bo[n];
#pragma unroll
    for (int mi = 0; mi < 4; ++mi)
#pragma unroll
      for (int r = 0; r < 4; ++r) {
        int m = m0 + wr * 64 + mi * 16 + fg * 4 + r;
        out[(size_t)m * 512 + n] = acc[mi][ni][r] + bias;
      }
  }
}

// ---------------------------------------------------------------- launcher
extern "C" void kernel_launch(void* const* d_in, const int* in_sizes, int n_in,
                              void* d_out, int out_size, void* d_ws, size_t ws_size,
                              hipStream_t stream) {
  const float* x = (const float*)d_in[0];
  const unsigned char* mask = (const unsigned char*)d_in[1];
  const float* Wq = (const float*)d_in[2];
  const float* bq = (const float*)d_in[3];
  const float* Wk = (const float*)d_in[4];
  const float* bk = (const float*)d_in[5];
  const float* Wv = (const float*)d_in[6];
  const float* bv = (const float*)d_in[7];
  const float* Wo = (const float*)d_in[8];
  const float* bo = (const float*)d_in[9];
  float* out = (float*)d_out;
  float* attn = out + (size_t)4 * 2048 * 512;

  char* ws = (char*)d_ws;
  size_t off = 0;
  u16* xb  = (u16*)(ws + off); off += (size_t)8192 * 512 * 2;   // x bf16
  u16* Wb  = (u16*)(ws + off); off += (size_t)1536 * 512 * 2;   // Wq|Wk|Wv bf16
  u16* Wob = (u16*)(ws + off); off += (size_t)512 * 512 * 2;    // Wo bf16
  u16* QK  = (u16*)(ws + off); off += (size_t)8192 * 1024 * 2;  // Q|K bf16
  u16* Vt  = (u16*)(ws + off); off += (size_t)2048 * 2048 * 2;  // V transposed
  u16* ctx = (u16*)(ws + off); off += (size_t)8192 * 512 * 2;   // attn@V bf16
  if (ws_size < off) return;  // insufficient workspace

  cvt_kernel<<<5120, 256, 0, stream>>>(x, Wq, Wk, Wv, Wo, xb, Wb, Wob);
  gemm_qkv<<<dim3(64, 12), 256, 0, stream>>>(xb, Wb, bq, bk, bv, QK, Vt);
  attn_kernel<<<512, 256, 0, stream>>>(QK, Vt, mask, attn, ctx);
  gemm_out<<<dim3(64, 4), 256, 0, stream>>>(ctx, Wob, bo, out);
}